// Round 7
// baseline (894.056 us; speedup 1.0000x reference)
//
#include <hip/hip_runtime.h>
#include <math.h>

#define NPATH 8192
#define NT    2048
#define NODES 384
#define VMIN  (-3.06f)
#define WIDTHV 6.62f            // VMAX - VMIN = 3.56 - (-3.06)
#define SFX   2.8853900817779268f   // 2*log2(e)
#define LFX   1.4426950408889634f   // log2(e)

typedef float v2f __attribute__((ext_vector_type(2)));
typedef float v4f __attribute__((ext_vector_type(4)));
typedef unsigned int u32x4 __attribute__((ext_vector_type(4)));
typedef _Float16 f16x8 __attribute__((ext_vector_type(8)));

// ws float layout
#define W2P_F   0        // v2f w2pairs[k*32+j] = {W2dr[j][k], W2df[j][k]}  (2048 floats)
#define W1VP_F  2048     // v2f w1v pairs [32]
#define W3P_F   2112     // v2f w3 pairs  [32]
#define B2P_F   2176     // v2f b2 pairs  [32]
#define CST_F   2240     // b3dr, b3df, dt
#define QTAB_B  16384    // byte offset: u32x4 qtab[path][i] = fp16 {f,g} nodes i-1..i+2 (48 MB)

__device__ __forceinline__ v2f vsplat(float x) { return (v2f){x, x}; }
__device__ __forceinline__ v2f vfma(v2f a, v2f b, v2f c) { return __builtin_elementwise_fma(a, b, c); }

__device__ __forceinline__ float tanh1(float z) {   // tanh(z) via exp2
    float e = __builtin_amdgcn_exp2f(SFX * z);
    return fmaf(__builtin_amdgcn_rcpf(1.0f + e), -2.0f, 1.0f);
}
__device__ __forceinline__ float sig1(float z) {    // sigmoid(z)
    float e = __builtin_amdgcn_exp2f(-LFX * z);
    return __builtin_amdgcn_rcpf(1.0f + e);
}
__device__ __forceinline__ v2f tanh2(v2f z) {
    v2f r; r.x = tanh1(z.x); r.y = tanh1(z.y); return r;
}

__global__ void prep_kernel(const float* __restrict__ drw1,
                            const float* __restrict__ drw2, const float* __restrict__ drb2,
                            const float* __restrict__ drw3, const float* __restrict__ drb3,
                            const float* __restrict__ dfw1,
                            const float* __restrict__ dfw2, const float* __restrict__ dfb2,
                            const float* __restrict__ dfw3, const float* __restrict__ dfb3,
                            const float* __restrict__ dtp, float* __restrict__ ws)
{
    int tid = threadIdx.x;
    for (int idx = tid; idx < 1024; idx += 256) {
        int k = idx >> 5, j = idx & 31;
        ws[W2P_F + 2 * idx]     = drw2[j * 32 + k];   // W2[j][k] pairs, k-major
        ws[W2P_F + 2 * idx + 1] = dfw2[j * 32 + k];
    }
    if (tid < 32) {
        ws[W1VP_F + 2 * tid]     = drw1[tid * 16 + 15];
        ws[W1VP_F + 2 * tid + 1] = dfw1[tid * 16 + 15];
        ws[W3P_F + 2 * tid]      = drw3[tid];
        ws[W3P_F + 2 * tid + 1]  = dfw3[tid];
        ws[B2P_F + 2 * tid]      = drb2[tid];
        ws[B2P_F + 2 * tid + 1]  = dfb2[tid];
    }
    if (tid == 0) {
        ws[CST_F]     = drb3[0];
        ws[CST_F + 1] = dfb3[0];
        ws[CST_F + 2] = dtp[0];
    }
}

// One block per path (384 lanes = 384 v-nodes). Each lane evaluates both nets
// fully at its node, then the block assembles fp16 quads {i-1..i+2} via LDS.
__global__ __attribute__((amdgpu_flat_work_group_size(NODES, NODES), amdgpu_waves_per_eu(2, 4)))
void build_kernel(const float* __restrict__ sig,
                  const float* __restrict__ drw1, const float* __restrict__ drb1,
                  const float* __restrict__ dfw1, const float* __restrict__ dfb1,
                  float* __restrict__ ws)
{
    const int p = blockIdx.x;
    const int i = threadIdx.x;
    __shared__ v2f spv[32];            // pre pairs {dr, df} per hidden unit
    __shared__ v2f nodes[NODES];       // per-node {drift*dt, diffusion}
    if (i < 64) {
        int j = i & 31, net = i >> 5;
        const float* w1 = net ? dfw1 : drw1;
        const float* b1 = net ? dfb1 : drb1;
        float acc = b1[j];
#pragma unroll
        for (int m = 0; m < 15; ++m) acc = fmaf(sig[p * 15 + m], w1[j * 16 + m], acc);
        ((float*)spv)[2 * j + net] = acc;
    }
    __syncthreads();

    const float v = VMIN + (WIDTHV / (float)(NODES - 1)) * (float)i;
    const v2f* __restrict__ w2p  = (const v2f*)(ws + W2P_F);
    const v2f* __restrict__ w1vp = (const v2f*)(ws + W1VP_F);
    const v2f* __restrict__ w3p  = (const v2f*)(ws + W3P_F);
    const v2f* __restrict__ b2p  = (const v2f*)(ws + B2P_F);

    v2f acc2[32];
#pragma unroll
    for (int j = 0; j < 32; ++j) acc2[j] = b2p[j];

#pragma unroll 4
    for (int k = 0; k < 32; ++k) {
        v2f pre = spv[k];                          // LDS broadcast
        v2f z   = vfma(vsplat(v), w1vp[k], pre);
        v2f h   = tanh2(z);
        const v2f* col = w2p + k * 32;             // uniform scalar loads
#pragma unroll
        for (int j = 0; j < 32; ++j) acc2[j] = vfma(col[j], h, acc2[j]);
    }

    v2f z3 = (v2f){ws[CST_F], ws[CST_F + 1]};
#pragma unroll
    for (int j = 0; j < 32; ++j) {
        v2f a2 = tanh2(acc2[j]);
        z3 = vfma(w3p[j], a2, z3);
    }
    float dt = ws[CST_F + 2];
    float fv = 3.0f * tanh1(z3.x) * dt;            // drift * dt
    float gv = sig1(z3.y) + 0.1f;                  // diffusion
    nodes[i] = (v2f){fv, gv};
    __syncthreads();

    // assemble fp16 quad {i-1, i, i+1, i+2} (edge-clamped; scan only uses i in [1,381])
    int im  = i - 1 < 0 ? 0 : i - 1;
    int ip  = i + 1 > NODES - 1 ? NODES - 1 : i + 1;
    int ip2 = i + 2 > NODES - 1 ? NODES - 1 : i + 2;
    v2f A = nodes[im], B = nodes[i], C = nodes[ip], D = nodes[ip2];
    f16x8 o;
    o[0] = (_Float16)A.x; o[1] = (_Float16)A.y;
    o[2] = (_Float16)B.x; o[3] = (_Float16)B.y;
    o[4] = (_Float16)C.x; o[5] = (_Float16)C.y;
    o[6] = (_Float16)D.x; o[7] = (_Float16)D.y;
    u32x4* qtab = (u32x4*)((char*)ws + QTAB_B);
    qtab[(size_t)p * NODES + i] = __builtin_bit_cast(u32x4, o);
}

// One lane per path. Per step: ONE dwordx4 loads the whole fp16 CR window,
// packed-f32 Catmull-Rom, then the scalar recurrence. dW/out nontemporal.
__global__ __launch_bounds__(64) void scan_kernel(
    const float* __restrict__ init_var,
    const float* __restrict__ dW,
    const float* __restrict__ ws,
    float* __restrict__ out)
{
    const int path = blockIdx.x * 64 + threadIdx.x;
    float lv = logf(fminf(fmaxf(init_var[path], 0.005f), 0.2f));
    const u32x4* __restrict__ tq = (const u32x4*)((const char*)ws + QTAB_B) + (size_t)path * NODES;
    const float* __restrict__ dwrow = dW + (size_t)path * NT;
    float* __restrict__ outp = out + path;

    const float INVD = (float)(NODES - 1) / WIDTHV;
    const float UOFF = (4.0f - VMIN) * INVD;       // u = lv*INVD + UOFF

    auto STEP = [&](float dw, int tt) {
        float u  = fmaf(lv, INVD, UOFF);
        float fi = floorf(u);
        int   i  = (int)fi;
        float w  = u - fi;
        i = i < 1 ? 1 : (i > NODES - 3 ? NODES - 3 : i);
        u32x4 q = tq[i];                            // single 16B gather
        f16x8 h = __builtin_bit_cast(f16x8, q);
        v2f m1 = (v2f){(float)h[0], (float)h[1]};
        v2f p0 = (v2f){(float)h[2], (float)h[3]};
        v2f p1 = (v2f){(float)h[4], (float)h[5]};
        v2f p2 = (v2f){(float)h[6], (float)h[7]};
        // Catmull-Rom: p0 + 0.5w*(d + w*(c2 + w*c3))
        v2f d  = p1 - m1;
        v2f c2 = (m1 + m1) - vsplat(5.0f) * p0 + vsplat(4.0f) * p1 - p2;
        v2f c3 = vsplat(3.0f) * (p0 - p1) + (p2 - m1);
        v2f val = vfma(vsplat(0.5f * w), vfma(vsplat(w), vfma(vsplat(w), c3, c2), d), p0);
        lv = fmaf(val.y, dw, lv + val.x);
        lv = fminf(fmaxf(lv, -7.0f), -0.5f);
        float ev = __builtin_amdgcn_exp2f(lv * LFX);
        __builtin_nontemporal_store(ev, outp + (size_t)tt * NPATH);
    };

    v4f dwc = __builtin_nontemporal_load((const v4f*)dwrow);
    for (int t = 0; t < NT; t += 4) {
        v4f dwn = {0.0f, 0.0f, 0.0f, 0.0f};
        if (t + 4 < NT) dwn = __builtin_nontemporal_load((const v4f*)(dwrow + t + 4));
        STEP(dwc.x, t);
        STEP(dwc.y, t + 1);
        STEP(dwc.z, t + 2);
        STEP(dwc.w, t + 3);
        dwc = dwn;
    }
}

extern "C" void kernel_launch(void* const* d_in, const int* in_sizes, int n_in,
                              void* d_out, int out_size, void* d_ws, size_t ws_size,
                              hipStream_t stream) {
    const float* init_var = (const float*)d_in[0];
    const float* sig      = (const float*)d_in[1];
    const float* dW       = (const float*)d_in[2];
    const float* dtp      = (const float*)d_in[3];
    const float* drw1     = (const float*)d_in[4];
    const float* drb1     = (const float*)d_in[5];
    const float* drw2     = (const float*)d_in[6];
    const float* drb2     = (const float*)d_in[7];
    const float* drw3     = (const float*)d_in[8];
    const float* drb3     = (const float*)d_in[9];
    const float* dfw1     = (const float*)d_in[10];
    const float* dfb1     = (const float*)d_in[11];
    const float* dfw2     = (const float*)d_in[12];
    const float* dfb2     = (const float*)d_in[13];
    const float* dfw3     = (const float*)d_in[14];
    const float* dfb3     = (const float*)d_in[15];
    float* out = (float*)d_out;
    float* ws  = (float*)d_ws;

    hipLaunchKernelGGL(prep_kernel, dim3(1), dim3(256), 0, stream,
                       drw1, drw2, drb2, drw3, drb3,
                       dfw1, dfw2, dfb2, dfw3, dfb3, dtp, ws);
    hipLaunchKernelGGL(build_kernel, dim3(NPATH), dim3(NODES), 0, stream,
                       sig, drw1, drb1, dfw1, dfb1, ws);
    hipLaunchKernelGGL(scan_kernel, dim3(NPATH / 64), dim3(64), 0, stream,
                       init_var, dW, ws, out);
}

// Round 8
// 671.804 us; speedup vs baseline: 1.3308x; 1.3308x over previous
//
#include <hip/hip_runtime.h>
#include <math.h>

#define NPATH 8192
#define NT    2048
#define NODES 384
#define VMIN  (-3.06f)
#define WIDTHV 6.62f            // VMAX - VMIN = 3.56 - (-3.06)
#define SFX   2.8853900817779268f   // 2*log2(e)
#define LFX   1.4426950408889634f   // log2(e)

typedef float v2f __attribute__((ext_vector_type(2)));
typedef float v4f __attribute__((ext_vector_type(4)));
typedef _Float16 f16x2 __attribute__((ext_vector_type(2)));

// ws float layout
#define W2P_F   0        // v2f w2pairs[k*32+j] = {W2dr[j][k], W2df[j][k]}  (2048 floats)
#define W1VP_F  2048     // v2f w1v pairs [32]
#define W3P_F   2112     // v2f w3 pairs  [32]
#define B2P_F   2176     // v2f b2 pairs  [32]
#define CST_F   2240     // b3dr, b3df, dt
#define GTAB_B  16384    // byte offset: u32 gtab[path][NODES] = fp16 {f,g} per node (12.6 MB)

__device__ __forceinline__ v2f vsplat(float x) { return (v2f){x, x}; }
__device__ __forceinline__ v2f vfma(v2f a, v2f b, v2f c) { return __builtin_elementwise_fma(a, b, c); }

__device__ __forceinline__ float tanh1(float z) {   // tanh(z) via exp2
    float e = __builtin_amdgcn_exp2f(SFX * z);
    return fmaf(__builtin_amdgcn_rcpf(1.0f + e), -2.0f, 1.0f);
}
__device__ __forceinline__ float sig1(float z) {    // sigmoid(z)
    float e = __builtin_amdgcn_exp2f(-LFX * z);
    return __builtin_amdgcn_rcpf(1.0f + e);
}
__device__ __forceinline__ v2f tanh2(v2f z) {
    v2f r; r.x = tanh1(z.x); r.y = tanh1(z.y); return r;
}
__device__ __forceinline__ v2f up16(unsigned int u) {
    f16x2 h = __builtin_bit_cast(f16x2, u);
    return (v2f){(float)h.x, (float)h.y};
}

__global__ void prep_kernel(const float* __restrict__ drw1,
                            const float* __restrict__ drw2, const float* __restrict__ drb2,
                            const float* __restrict__ drw3, const float* __restrict__ drb3,
                            const float* __restrict__ dfw1,
                            const float* __restrict__ dfw2, const float* __restrict__ dfb2,
                            const float* __restrict__ dfw3, const float* __restrict__ dfb3,
                            const float* __restrict__ dtp, float* __restrict__ ws)
{
    int tid = threadIdx.x;
    for (int idx = tid; idx < 1024; idx += 256) {
        int k = idx >> 5, j = idx & 31;
        ws[W2P_F + 2 * idx]     = drw2[j * 32 + k];   // W2[j][k] pairs, k-major
        ws[W2P_F + 2 * idx + 1] = dfw2[j * 32 + k];
    }
    if (tid < 32) {
        ws[W1VP_F + 2 * tid]     = drw1[tid * 16 + 15];
        ws[W1VP_F + 2 * tid + 1] = dfw1[tid * 16 + 15];
        ws[W3P_F + 2 * tid]      = drw3[tid];
        ws[W3P_F + 2 * tid + 1]  = dfw3[tid];
        ws[B2P_F + 2 * tid]      = drb2[tid];
        ws[B2P_F + 2 * tid + 1]  = dfb2[tid];
    }
    if (tid == 0) {
        ws[CST_F]     = drb3[0];
        ws[CST_F + 1] = dfb3[0];
        ws[CST_F + 2] = dtp[0];
    }
}

// One block per path (384 lanes = 384 v-nodes). Each lane evaluates both nets
// fully at its node and writes one fp16 {drift*dt, diffusion} pair.
__global__ __attribute__((amdgpu_flat_work_group_size(NODES, NODES), amdgpu_waves_per_eu(2, 4)))
void build_kernel(const float* __restrict__ sig,
                  const float* __restrict__ drw1, const float* __restrict__ drb1,
                  const float* __restrict__ dfw1, const float* __restrict__ dfb1,
                  float* __restrict__ ws)
{
    const int p = blockIdx.x;
    const int i = threadIdx.x;
    __shared__ v2f spv[32];            // pre pairs {dr, df} per hidden unit
    if (i < 64) {
        int j = i & 31, net = i >> 5;
        const float* w1 = net ? dfw1 : drw1;
        const float* b1 = net ? dfb1 : drb1;
        float acc = b1[j];
#pragma unroll
        for (int m = 0; m < 15; ++m) acc = fmaf(sig[p * 15 + m], w1[j * 16 + m], acc);
        ((float*)spv)[2 * j + net] = acc;
    }
    __syncthreads();

    const float v = VMIN + (WIDTHV / (float)(NODES - 1)) * (float)i;
    const v2f* __restrict__ w2p  = (const v2f*)(ws + W2P_F);
    const v2f* __restrict__ w1vp = (const v2f*)(ws + W1VP_F);
    const v2f* __restrict__ w3p  = (const v2f*)(ws + W3P_F);
    const v2f* __restrict__ b2p  = (const v2f*)(ws + B2P_F);

    v2f acc2[32];
#pragma unroll
    for (int j = 0; j < 32; ++j) acc2[j] = b2p[j];

#pragma unroll 4
    for (int k = 0; k < 32; ++k) {
        v2f pre = spv[k];                          // LDS broadcast
        v2f z   = vfma(vsplat(v), w1vp[k], pre);
        v2f h   = tanh2(z);
        const v2f* col = w2p + k * 32;             // uniform scalar loads
#pragma unroll
        for (int j = 0; j < 32; ++j) acc2[j] = vfma(col[j], h, acc2[j]);
    }

    v2f z3 = (v2f){ws[CST_F], ws[CST_F + 1]};
#pragma unroll
    for (int j = 0; j < 32; ++j) {
        v2f a2 = tanh2(acc2[j]);
        z3 = vfma(w3p[j], a2, z3);
    }
    float dt = ws[CST_F + 2];
    float fv = 3.0f * tanh1(z3.x) * dt;            // drift * dt
    float gv = sig1(z3.y) + 0.1f;                  // diffusion
    f16x2 o; o.x = (_Float16)fv; o.y = (_Float16)gv;
    unsigned int* gtab = (unsigned int*)((char*)ws + GTAB_B);
    gtab[(size_t)p * NODES + i] = __builtin_bit_cast(unsigned int, o);
}

// One lane per path, 64 paths per block. Each path's fp16 node table lives in
// LDS (stride 385 dwords: 385 % 32 == 1 -> per-lane banks perfectly spread).
// Per step: 4 adjacent ds_read dwords (~120 cyc) replace the ~700-cyc global
// gather on the serial dependence chain.
__global__ __launch_bounds__(64) void scan_kernel(
    const float* __restrict__ init_var,
    const float* __restrict__ dW,
    const float* __restrict__ ws,
    float* __restrict__ out)
{
    __shared__ unsigned int tab[64][NODES + 1];    // 64 x 385 dwords = 96.25 KB
    const int lane  = threadIdx.x;
    const int pbase = blockIdx.x * 64;
    const unsigned int* __restrict__ gt = (const unsigned int*)((const char*)ws + GTAB_B);

    // cooperative, coalesced global -> LDS table copy (64 rows x 384 dwords)
    for (int p = 0; p < 64; ++p) {
        const unsigned int* row = gt + (size_t)(pbase + p) * NODES;
#pragma unroll
        for (int k = 0; k < NODES / 64; ++k)
            tab[p][k * 64 + lane] = row[k * 64 + lane];
    }
    __syncthreads();

    const int path = pbase + lane;
    float lv = logf(fminf(fmaxf(init_var[path], 0.005f), 0.2f));
    const float* __restrict__ dwrow = dW + (size_t)path * NT;
    float* __restrict__ outp = out + path;

    const float INVD = (float)(NODES - 1) / WIDTHV;
    const float UOFF = (4.0f - VMIN) * INVD;       // u = lv*INVD + UOFF; u in [3.4, 379.7]
    const unsigned int* __restrict__ tb = &tab[lane][0];

    auto STEP = [&](float dw, int tt) {
        float u  = fmaf(lv, INVD, UOFF);
        int   i  = (int)u;                          // trunc == floor (u > 0)
        float w  = u - (float)i;
        const unsigned int* n = tb + (i - 1);
        unsigned int qa = n[0], qb = n[1], qc = n[2], qd = n[3];
        v2f m1 = up16(qa), p0 = up16(qb), p1 = up16(qc), p2 = up16(qd);
        // Catmull-Rom: p0 + 0.5w*(d + w*(c2 + w*c3))
        v2f d  = p1 - m1;
        v2f c2 = (m1 + m1) - vsplat(5.0f) * p0 + vsplat(4.0f) * p1 - p2;
        v2f c3 = vsplat(3.0f) * (p0 - p1) + (p2 - m1);
        v2f val = vfma(vsplat(0.5f * w), vfma(vsplat(w), vfma(vsplat(w), c3, c2), d), p0);
        lv = fmaf(val.y, dw, lv + val.x);
        lv = fminf(fmaxf(lv, -7.0f), -0.5f);
        float ev = __builtin_amdgcn_exp2f(lv * LFX);
        __builtin_nontemporal_store(ev, outp + (size_t)tt * NPATH);
    };

    v4f dwc = __builtin_nontemporal_load((const v4f*)dwrow);
    for (int t = 0; t < NT; t += 4) {
        v4f dwn = {0.0f, 0.0f, 0.0f, 0.0f};
        if (t + 4 < NT) dwn = __builtin_nontemporal_load((const v4f*)(dwrow + t + 4));
        STEP(dwc.x, t);
        STEP(dwc.y, t + 1);
        STEP(dwc.z, t + 2);
        STEP(dwc.w, t + 3);
        dwc = dwn;
    }
}

extern "C" void kernel_launch(void* const* d_in, const int* in_sizes, int n_in,
                              void* d_out, int out_size, void* d_ws, size_t ws_size,
                              hipStream_t stream) {
    const float* init_var = (const float*)d_in[0];
    const float* sig      = (const float*)d_in[1];
    const float* dW       = (const float*)d_in[2];
    const float* dtp      = (const float*)d_in[3];
    const float* drw1     = (const float*)d_in[4];
    const float* drb1     = (const float*)d_in[5];
    const float* drw2     = (const float*)d_in[6];
    const float* drb2     = (const float*)d_in[7];
    const float* drw3     = (const float*)d_in[8];
    const float* drb3     = (const float*)d_in[9];
    const float* dfw1     = (const float*)d_in[10];
    const float* dfb1     = (const float*)d_in[11];
    const float* dfw2     = (const float*)d_in[12];
    const float* dfb2     = (const float*)d_in[13];
    const float* dfw3     = (const float*)d_in[14];
    const float* dfb3     = (const float*)d_in[15];
    float* out = (float*)d_out;
    float* ws  = (float*)d_ws;

    hipLaunchKernelGGL(prep_kernel, dim3(1), dim3(256), 0, stream,
                       drw1, drw2, drb2, drw3, drb3,
                       dfw1, dfw2, dfb2, dfw3, dfb3, dtp, ws);
    hipLaunchKernelGGL(build_kernel, dim3(NPATH), dim3(NODES), 0, stream,
                       sig, drw1, drb1, dfw1, dfb1, ws);
    hipLaunchKernelGGL(scan_kernel, dim3(NPATH / 64), dim3(64), 0, stream,
                       init_var, dW, ws, out);
}

// Round 9
// 503.610 us; speedup vs baseline: 1.7753x; 1.3340x over previous
//
#include <hip/hip_runtime.h>
#include <math.h>

#define NPATH 8192
#define NT    2048
#define NODES 384
#define VMIN  (-3.06f)
#define WIDTHV 6.62f            // VMAX - VMIN = 3.56 - (-3.06)
#define SFX   2.8853900817779268f   // 2*log2(e)
#define LFX   1.4426950408889634f   // log2(e)

typedef float v2f __attribute__((ext_vector_type(2)));
typedef float v4f __attribute__((ext_vector_type(4)));
typedef _Float16 f16x2 __attribute__((ext_vector_type(2)));

// ws float layout
#define W2P_F   0        // v2f w2pairs[k*32+j] = {W2dr[j][k], W2df[j][k]}  (2048 floats)
#define W1VP_F  2048     // v2f w1v pairs [32]
#define W3P_F   2112     // v2f w3 pairs  [32]
#define B2P_F   2176     // v2f b2 pairs  [32]
#define CST_F   2240     // b3dr, b3df, dt
#define WCONST_N 2244
#define GTAB_B  16384    // byte offset: u32 gtab[path][NODES] = fp16 {f,g} per node (12.6 MB)

__device__ __forceinline__ v2f vsplat(float x) { return (v2f){x, x}; }
__device__ __forceinline__ v2f vfma(v2f a, v2f b, v2f c) { return __builtin_elementwise_fma(a, b, c); }

__device__ __forceinline__ float tanh1(float z) {   // tanh(z) via exp2
    float e = __builtin_amdgcn_exp2f(SFX * z);
    return fmaf(__builtin_amdgcn_rcpf(1.0f + e), -2.0f, 1.0f);
}
__device__ __forceinline__ float sig1(float z) {    // sigmoid(z)
    float e = __builtin_amdgcn_exp2f(-LFX * z);
    return __builtin_amdgcn_rcpf(1.0f + e);
}
__device__ __forceinline__ v2f tanh2(v2f z) {
    v2f r; r.x = tanh1(z.x); r.y = tanh1(z.y); return r;
}
__device__ __forceinline__ v2f up16(unsigned int u) {
    f16x2 h = __builtin_bit_cast(f16x2, u);
    return (v2f){(float)h.x, (float)h.y};
}

__global__ void prep_kernel(const float* __restrict__ drw1,
                            const float* __restrict__ drw2, const float* __restrict__ drb2,
                            const float* __restrict__ drw3, const float* __restrict__ drb3,
                            const float* __restrict__ dfw1,
                            const float* __restrict__ dfw2, const float* __restrict__ dfb2,
                            const float* __restrict__ dfw3, const float* __restrict__ dfb3,
                            const float* __restrict__ dtp, float* __restrict__ ws)
{
    int tid = threadIdx.x;
    for (int idx = tid; idx < 1024; idx += 256) {
        int k = idx >> 5, j = idx & 31;
        ws[W2P_F + 2 * idx]     = drw2[j * 32 + k];   // W2[j][k] pairs, k-major
        ws[W2P_F + 2 * idx + 1] = dfw2[j * 32 + k];
    }
    if (tid < 32) {
        ws[W1VP_F + 2 * tid]     = drw1[tid * 16 + 15];
        ws[W1VP_F + 2 * tid + 1] = dfw1[tid * 16 + 15];
        ws[W3P_F + 2 * tid]      = drw3[tid];
        ws[W3P_F + 2 * tid + 1]  = dfw3[tid];
        ws[B2P_F + 2 * tid]      = drb2[tid];
        ws[B2P_F + 2 * tid + 1]  = dfb2[tid];
    }
    if (tid == 0) {
        ws[CST_F]     = drb3[0];
        ws[CST_F + 1] = dfb3[0];
        ws[CST_F + 2] = dtp[0];
    }
}

// One block per path (384 lanes = 384 v-nodes). Weights staged in LDS
// (wconst/gtab split pointers so the compiler can keep loads scalar and
// doesn't re-issue VMEM per use against the gtab alias).
__global__ __attribute__((amdgpu_flat_work_group_size(NODES, NODES)))
void build_kernel(const float* __restrict__ sig,
                  const float* __restrict__ drw1, const float* __restrict__ drb1,
                  const float* __restrict__ dfw1, const float* __restrict__ dfb1,
                  const float* __restrict__ wconst, unsigned int* __restrict__ gtab)
{
    const int p = blockIdx.x;
    const int i = threadIdx.x;
    __shared__ float lws[WCONST_N];
    __shared__ v2f spv[32];            // pre pairs {dr, df} per hidden unit
    for (int idx = i; idx < WCONST_N; idx += NODES) lws[idx] = wconst[idx];
    if (i < 64) {
        int j = i & 31, net = i >> 5;
        const float* w1 = net ? dfw1 : drw1;
        const float* b1 = net ? dfb1 : drb1;
        float acc = b1[j];
#pragma unroll
        for (int m = 0; m < 15; ++m) acc = fmaf(sig[p * 15 + m], w1[j * 16 + m], acc);
        ((float*)spv)[2 * j + net] = acc;
    }
    __syncthreads();

    const float v = VMIN + (WIDTHV / (float)(NODES - 1)) * (float)i;
    const v2f* __restrict__ w2p  = (const v2f*)(lws + W2P_F);
    const v2f* __restrict__ w1vp = (const v2f*)(lws + W1VP_F);
    const v2f* __restrict__ w3p  = (const v2f*)(lws + W3P_F);
    const v2f* __restrict__ b2p  = (const v2f*)(lws + B2P_F);

    v2f acc2[32];
#pragma unroll
    for (int j = 0; j < 32; ++j) acc2[j] = b2p[j];

#pragma unroll 4
    for (int k = 0; k < 32; ++k) {
        v2f pre = spv[k];                          // LDS broadcast
        v2f z   = vfma(vsplat(v), w1vp[k], pre);
        v2f h   = tanh2(z);
        const v2f* col = w2p + k * 32;             // LDS broadcast reads
#pragma unroll
        for (int j = 0; j < 32; ++j) acc2[j] = vfma(col[j], h, acc2[j]);
    }

    v2f z3 = (v2f){lws[CST_F], lws[CST_F + 1]};
#pragma unroll
    for (int j = 0; j < 32; ++j) {
        v2f a2 = tanh2(acc2[j]);
        z3 = vfma(w3p[j], a2, z3);
    }
    float dt = lws[CST_F + 2];
    float fv = 3.0f * tanh1(z3.x) * dt;            // drift * dt
    float gv = sig1(z3.y) + 0.1f;                  // diffusion
    f16x2 o; o.x = (_Float16)fv; o.y = (_Float16)gv;
    gtab[(size_t)p * NODES + i] = __builtin_bit_cast(unsigned int, o);
}

// One lane per path, 64 paths per block. Table transposed in LDS:
// tab[node][lane] -> every read hits bank lane%32 (2-way across the wave =
// free) regardless of the data-dependent node index. dW runs through a
// 16-step register pipeline (4 v4f in flight) so its HBM latency never
// lands on the recurrence chain.
__global__ __launch_bounds__(64) void scan_kernel(
    const float* __restrict__ init_var,
    const float* __restrict__ dW,
    const float* __restrict__ ws,
    float* __restrict__ out)
{
    __shared__ unsigned int tab[NODES][64];        // 96 KB, transposed
    const int lane  = threadIdx.x;
    const int pbase = blockIdx.x * 64;
    const unsigned int* __restrict__ gt = (const unsigned int*)((const char*)ws + GTAB_B);

    // coalesced global read; transposed LDS write (64-way conflict, one-time)
    for (int p = 0; p < 64; ++p) {
        const unsigned int* row = gt + (size_t)(pbase + p) * NODES;
#pragma unroll
        for (int k = 0; k < NODES / 64; ++k)
            tab[k * 64 + lane][p] = row[k * 64 + lane];
    }
    __syncthreads();

    const int path = pbase + lane;
    float lv = logf(fminf(fmaxf(init_var[path], 0.005f), 0.2f));
    const float* __restrict__ dwrow = dW + (size_t)path * NT;
    float* __restrict__ outp = out + path;

    const float INVD = (float)(NODES - 1) / WIDTHV;
    const float UOFF = (4.0f - VMIN) * INVD;       // u in [3.4, 379.5] -> no clamp needed
    const unsigned int* __restrict__ tcol = &tab[0][lane];

    auto STEP = [&](float dw, int tt) {
        float u  = fmaf(lv, INVD, UOFF);
        int   i  = (int)u;                          // trunc == floor (u > 0)
        float w  = u - (float)i;
        const unsigned int* n = tcol + (size_t)(i - 1) * 64;
        unsigned int qa = n[0], qb = n[64], qc = n[128], qd = n[192];
        v2f m1 = up16(qa), p0 = up16(qb), p1 = up16(qc), p2 = up16(qd);
        // Catmull-Rom: p0 + 0.5w*(d + w*(c2 + w*c3))
        v2f d  = p1 - m1;
        v2f c2 = (m1 + m1) - vsplat(5.0f) * p0 + vsplat(4.0f) * p1 - p2;
        v2f c3 = vsplat(3.0f) * (p0 - p1) + (p2 - m1);
        v2f val = vfma(vsplat(0.5f * w), vfma(vsplat(w), vfma(vsplat(w), c3, c2), d), p0);
        lv = fmaf(val.y, dw, lv + val.x);
        lv = fminf(fmaxf(lv, -7.0f), -0.5f);
        float ev = __builtin_amdgcn_exp2f(lv * LFX);
        __builtin_nontemporal_store(ev, outp + (size_t)tt * NPATH);
    };

    // 16-step-deep dW register pipeline (plain cached loads; lines reused 4x)
    v4f buf0 = *(const v4f*)(dwrow + 0);
    v4f buf1 = *(const v4f*)(dwrow + 4);
    v4f buf2 = *(const v4f*)(dwrow + 8);
    v4f buf3 = *(const v4f*)(dwrow + 12);
    for (int t = 0; t < NT; t += 4) {
        v4f cur = buf0;
        buf0 = buf1; buf1 = buf2; buf2 = buf3;
        if (t + 16 < NT) buf3 = *(const v4f*)(dwrow + t + 16);
        STEP(cur.x, t);
        STEP(cur.y, t + 1);
        STEP(cur.z, t + 2);
        STEP(cur.w, t + 3);
    }
}

extern "C" void kernel_launch(void* const* d_in, const int* in_sizes, int n_in,
                              void* d_out, int out_size, void* d_ws, size_t ws_size,
                              hipStream_t stream) {
    const float* init_var = (const float*)d_in[0];
    const float* sig      = (const float*)d_in[1];
    const float* dW       = (const float*)d_in[2];
    const float* dtp      = (const float*)d_in[3];
    const float* drw1     = (const float*)d_in[4];
    const float* drb1     = (const float*)d_in[5];
    const float* drw2     = (const float*)d_in[6];
    const float* drb2     = (const float*)d_in[7];
    const float* drw3     = (const float*)d_in[8];
    const float* drb3     = (const float*)d_in[9];
    const float* dfw1     = (const float*)d_in[10];
    const float* dfb1     = (const float*)d_in[11];
    const float* dfw2     = (const float*)d_in[12];
    const float* dfb2     = (const float*)d_in[13];
    const float* dfw3     = (const float*)d_in[14];
    const float* dfb3     = (const float*)d_in[15];
    float* out = (float*)d_out;
    float* ws  = (float*)d_ws;

    hipLaunchKernelGGL(prep_kernel, dim3(1), dim3(256), 0, stream,
                       drw1, drw2, drb2, drw3, drb3,
                       dfw1, dfw2, dfb2, dfw3, dfb3, dtp, ws);
    hipLaunchKernelGGL(build_kernel, dim3(NPATH), dim3(NODES), 0, stream,
                       sig, drw1, drb1, dfw1, dfb1,
                       ws, (unsigned int*)((char*)ws + GTAB_B));
    hipLaunchKernelGGL(scan_kernel, dim3(NPATH / 64), dim3(64), 0, stream,
                       init_var, dW, ws, out);
}

// Round 10
// 494.829 us; speedup vs baseline: 1.8068x; 1.0177x over previous
//
#include <hip/hip_runtime.h>
#include <math.h>

#define NPATH 8192
#define NT    2048
#define NODES 384
#define VMIN  (-3.06f)
#define WIDTHV 6.62f            // VMAX - VMIN = 3.56 - (-3.06)
#define SFX   2.8853900817779268f   // 2*log2(e)
#define LFX   1.4426950408889634f   // log2(e)

typedef float v2f __attribute__((ext_vector_type(2)));
typedef float v4f __attribute__((ext_vector_type(4)));
typedef _Float16 f16x2 __attribute__((ext_vector_type(2)));

// ws float layout
#define W2P_F   0        // v2f w2pairs[k*32+j] = {W2dr[j][k], W2df[j][k]}  (2048 floats)
#define W1VP_F  2048     // v2f w1v pairs [32]
#define W3P_F   2112     // v2f w3 pairs  [32]
#define B2P_F   2176     // v2f b2 pairs  [32]
#define CST_F   2240     // b3dr, b3df, dt
#define GTAB_B  16384    // byte offset: u32 gtab[path][NODES] = fp16 {f,g} per node (12.6 MB)

__device__ __forceinline__ v2f vsplat(float x) { return (v2f){x, x}; }
__device__ __forceinline__ v2f vfma(v2f a, v2f b, v2f c) { return __builtin_elementwise_fma(a, b, c); }

__device__ __forceinline__ float tanh1(float z) {   // tanh(z) via exp2
    float e = __builtin_amdgcn_exp2f(SFX * z);
    return fmaf(__builtin_amdgcn_rcpf(1.0f + e), -2.0f, 1.0f);
}
__device__ __forceinline__ float sig1(float z) {    // sigmoid(z)
    float e = __builtin_amdgcn_exp2f(-LFX * z);
    return __builtin_amdgcn_rcpf(1.0f + e);
}
__device__ __forceinline__ v2f tanh2(v2f z) {
    v2f r; r.x = tanh1(z.x); r.y = tanh1(z.y); return r;
}
__device__ __forceinline__ v2f up16(unsigned int u) {
    f16x2 h = __builtin_bit_cast(f16x2, u);
    return (v2f){(float)h.x, (float)h.y};
}

__global__ void prep_kernel(const float* __restrict__ drw1,
                            const float* __restrict__ drw2, const float* __restrict__ drb2,
                            const float* __restrict__ drw3, const float* __restrict__ drb3,
                            const float* __restrict__ dfw1,
                            const float* __restrict__ dfw2, const float* __restrict__ dfb2,
                            const float* __restrict__ dfw3, const float* __restrict__ dfb3,
                            const float* __restrict__ dtp, float* __restrict__ ws)
{
    int tid = threadIdx.x;
    for (int idx = tid; idx < 1024; idx += 256) {
        int k = idx >> 5, j = idx & 31;
        ws[W2P_F + 2 * idx]     = drw2[j * 32 + k];   // W2[j][k] pairs, k-major
        ws[W2P_F + 2 * idx + 1] = dfw2[j * 32 + k];
    }
    if (tid < 32) {
        ws[W1VP_F + 2 * tid]     = drw1[tid * 16 + 15];
        ws[W1VP_F + 2 * tid + 1] = dfw1[tid * 16 + 15];
        ws[W3P_F + 2 * tid]      = drw3[tid];
        ws[W3P_F + 2 * tid + 1]  = dfw3[tid];
        ws[B2P_F + 2 * tid]      = drb2[tid];
        ws[B2P_F + 2 * tid + 1]  = dfb2[tid];
    }
    if (tid == 0) {
        ws[CST_F]     = drb3[0];
        ws[CST_F + 1] = dfb3[0];
        ws[CST_F + 2] = dtp[0];
    }
}

// One block per path (384 lanes = 384 v-nodes). Weights read through the
// GLOBAL wconst pointer with wave-uniform indices -> compiler emits pipelined
// s_loads (SMEM pipe), not per-lane VMEM and not DS broadcasts (round-9
// regression). Output units processed in 2 passes of 16 accumulators
// (32 VGPRs) with h recomputed per pass -> no 64-VGPR live array, no spills.
__global__ __attribute__((amdgpu_flat_work_group_size(384, 384), amdgpu_waves_per_eu(4)))
void build_kernel(const float* __restrict__ sig,
                  const float* __restrict__ drw1, const float* __restrict__ drb1,
                  const float* __restrict__ dfw1, const float* __restrict__ dfb1,
                  const float* __restrict__ wconst, unsigned int* __restrict__ gtab)
{
    const int p = blockIdx.x;
    const int i = threadIdx.x;
    __shared__ v2f spv[32];            // pre pairs {dr, df} per hidden unit
    if (i < 64) {
        int j = i & 31, net = i >> 5;
        const float* w1 = net ? dfw1 : drw1;
        const float* b1 = net ? dfb1 : drb1;
        float acc = b1[j];
#pragma unroll
        for (int m = 0; m < 15; ++m) acc = fmaf(sig[p * 15 + m], w1[j * 16 + m], acc);
        ((float*)spv)[2 * j + net] = acc;
    }
    __syncthreads();

    const float v = VMIN + (WIDTHV / (float)(NODES - 1)) * (float)i;
    const v2f* __restrict__ w2p  = (const v2f*)(wconst + W2P_F);
    const v2f* __restrict__ w1vp = (const v2f*)(wconst + W1VP_F);
    const v2f* __restrict__ w3p  = (const v2f*)(wconst + W3P_F);
    const v2f* __restrict__ b2p  = (const v2f*)(wconst + B2P_F);

    v2f z3 = (v2f){wconst[CST_F], wconst[CST_F + 1]};

#pragma unroll
    for (int c = 0; c < 2; ++c) {          // two chunks of 16 output units
        v2f acc[16];
#pragma unroll
        for (int j = 0; j < 16; ++j) acc[j] = b2p[c * 16 + j];

#pragma unroll 8
        for (int k = 0; k < 32; ++k) {     // h recomputed per chunk (no big live array)
            v2f pre = spv[k];              // LDS broadcast (uniform addr)
            v2f z   = vfma(vsplat(v), w1vp[k], pre);
            v2f h   = tanh2(z);
            const v2f* col = w2p + k * 32 + c * 16;   // uniform -> s_load
#pragma unroll
            for (int j = 0; j < 16; ++j) acc[j] = vfma(col[j], h, acc[j]);
        }
#pragma unroll
        for (int j = 0; j < 16; ++j) {
            v2f a2 = tanh2(acc[j]);
            z3 = vfma(w3p[c * 16 + j], a2, z3);
        }
    }

    float dt = wconst[CST_F + 2];
    float fv = 3.0f * tanh1(z3.x) * dt;            // drift * dt
    float gv = sig1(z3.y) + 0.1f;                  // diffusion
    f16x2 o; o.x = (_Float16)fv; o.y = (_Float16)gv;
    gtab[(size_t)p * NODES + i] = __builtin_bit_cast(unsigned int, o);
}

// One lane per path, 64 paths per block. Table transposed in LDS:
// tab[node][lane] -> every read hits bank lane%32 (2-way across the wave =
// free) regardless of the data-dependent node index. dW runs through a
// 16-step register pipeline (4 v4f in flight) so its HBM latency never
// lands on the recurrence chain.
__global__ __launch_bounds__(64) void scan_kernel(
    const float* __restrict__ init_var,
    const float* __restrict__ dW,
    const float* __restrict__ ws,
    float* __restrict__ out)
{
    __shared__ unsigned int tab[NODES][64];        // 96 KB, transposed
    const int lane  = threadIdx.x;
    const int pbase = blockIdx.x * 64;
    const unsigned int* __restrict__ gt = (const unsigned int*)((const char*)ws + GTAB_B);

    // coalesced global read; transposed LDS write (64-way conflict, one-time)
    for (int p = 0; p < 64; ++p) {
        const unsigned int* row = gt + (size_t)(pbase + p) * NODES;
#pragma unroll
        for (int k = 0; k < NODES / 64; ++k)
            tab[k * 64 + lane][p] = row[k * 64 + lane];
    }
    __syncthreads();

    const int path = pbase + lane;
    float lv = logf(fminf(fmaxf(init_var[path], 0.005f), 0.2f));
    const float* __restrict__ dwrow = dW + (size_t)path * NT;
    float* __restrict__ outp = out + path;

    const float INVD = (float)(NODES - 1) / WIDTHV;
    const float UOFF = (4.0f - VMIN) * INVD;       // u in [3.4, 379.5] -> no clamp needed
    const unsigned int* __restrict__ tcol = &tab[0][lane];

    auto STEP = [&](float dw, int tt) {
        float u  = fmaf(lv, INVD, UOFF);
        int   i  = (int)u;                          // trunc == floor (u > 0)
        float w  = u - (float)i;
        const unsigned int* n = tcol + (size_t)(i - 1) * 64;
        unsigned int qa = n[0], qb = n[64], qc = n[128], qd = n[192];
        v2f m1 = up16(qa), p0 = up16(qb), p1 = up16(qc), p2 = up16(qd);
        // Catmull-Rom: p0 + 0.5w*(d + w*(c2 + w*c3))
        v2f d  = p1 - m1;
        v2f c2 = (m1 + m1) - vsplat(5.0f) * p0 + vsplat(4.0f) * p1 - p2;
        v2f c3 = vsplat(3.0f) * (p0 - p1) + (p2 - m1);
        v2f val = vfma(vsplat(0.5f * w), vfma(vsplat(w), vfma(vsplat(w), c3, c2), d), p0);
        lv = fmaf(val.y, dw, lv + val.x);
        lv = fminf(fmaxf(lv, -7.0f), -0.5f);
        float ev = __builtin_amdgcn_exp2f(lv * LFX);
        __builtin_nontemporal_store(ev, outp + (size_t)tt * NPATH);
    };

    // 16-step-deep dW register pipeline (plain cached loads; lines reused 4x)
    v4f buf0 = *(const v4f*)(dwrow + 0);
    v4f buf1 = *(const v4f*)(dwrow + 4);
    v4f buf2 = *(const v4f*)(dwrow + 8);
    v4f buf3 = *(const v4f*)(dwrow + 12);
    for (int t = 0; t < NT; t += 4) {
        v4f cur = buf0;
        buf0 = buf1; buf1 = buf2; buf2 = buf3;
        if (t + 16 < NT) buf3 = *(const v4f*)(dwrow + t + 16);
        STEP(cur.x, t);
        STEP(cur.y, t + 1);
        STEP(cur.z, t + 2);
        STEP(cur.w, t + 3);
    }
}

extern "C" void kernel_launch(void* const* d_in, const int* in_sizes, int n_in,
                              void* d_out, int out_size, void* d_ws, size_t ws_size,
                              hipStream_t stream) {
    const float* init_var = (const float*)d_in[0];
    const float* sig      = (const float*)d_in[1];
    const float* dW       = (const float*)d_in[2];
    const float* dtp      = (const float*)d_in[3];
    const float* drw1     = (const float*)d_in[4];
    const float* drb1     = (const float*)d_in[5];
    const float* drw2     = (const float*)d_in[6];
    const float* drb2     = (const float*)d_in[7];
    const float* drw3     = (const float*)d_in[8];
    const float* drb3     = (const float*)d_in[9];
    const float* dfw1     = (const float*)d_in[10];
    const float* dfb1     = (const float*)d_in[11];
    const float* dfw2     = (const float*)d_in[12];
    const float* dfb2     = (const float*)d_in[13];
    const float* dfw3     = (const float*)d_in[14];
    const float* dfb3     = (const float*)d_in[15];
    float* out = (float*)d_out;
    float* ws  = (float*)d_ws;

    hipLaunchKernelGGL(prep_kernel, dim3(1), dim3(256), 0, stream,
                       drw1, drw2, drb2, drw3, drb3,
                       dfw1, dfw2, dfb2, dfw3, dfb3, dtp, ws);
    hipLaunchKernelGGL(build_kernel, dim3(NPATH), dim3(NODES), 0, stream,
                       sig, drw1, drb1, dfw1, dfb1,
                       ws, (unsigned int*)((char*)ws + GTAB_B));
    hipLaunchKernelGGL(scan_kernel, dim3(NPATH / 64), dim3(64), 0, stream,
                       init_var, dW, ws, out);
}

// Round 11
// 357.029 us; speedup vs baseline: 2.5042x; 1.3860x over previous
//
#include <hip/hip_runtime.h>
#include <math.h>

#define NPATH 8192
#define NT    2048
#define NODES 192
#define VMIN  (-3.06f)
#define WIDTHV 6.62f            // VMAX - VMIN = 3.56 - (-3.06)
#define SFX   2.8853900817779268f   // 2*log2(e)
#define LFX   1.4426950408889634f   // log2(e)
#define INVD  ((float)(NODES - 1) / WIDTHV)
#define UOFFC ((4.0f - VMIN) * INVD)

typedef float v2f __attribute__((ext_vector_type(2)));
typedef float v4f __attribute__((ext_vector_type(4)));
typedef _Float16 f16x2 __attribute__((ext_vector_type(2)));

// ws float layout
#define W2P_F   0        // v2f w2pairs[k*32+j] = {W2dr[j][k], W2df[j][k]}  (2048 floats)
#define W1VP_F  2048     // v2f w1v pairs [32]
#define W3P_F   2112     // v2f w3 pairs  [32]
#define B2P_F   2176     // v2f b2 pairs  [32]
#define CST_F   2240     // b3dr, b3df, dt
#define GTAB_B  16384    // byte offset: u32 gtab[path][NODES] = fp16 {f*INVD, g*INVD} per node

__device__ __forceinline__ v2f vsplat(float x) { return (v2f){x, x}; }
__device__ __forceinline__ v2f vfma(v2f a, v2f b, v2f c) { return __builtin_elementwise_fma(a, b, c); }

__device__ __forceinline__ float tanh1(float z) {   // tanh(z) via exp2
    float e = __builtin_amdgcn_exp2f(SFX * z);
    return fmaf(__builtin_amdgcn_rcpf(1.0f + e), -2.0f, 1.0f);
}
__device__ __forceinline__ float sig1(float z) {    // sigmoid(z)
    float e = __builtin_amdgcn_exp2f(-LFX * z);
    return __builtin_amdgcn_rcpf(1.0f + e);
}
__device__ __forceinline__ v2f tanh2(v2f z) {
    v2f r; r.x = tanh1(z.x); r.y = tanh1(z.y); return r;
}
__device__ __forceinline__ v2f up16(unsigned int u) {
    f16x2 h = __builtin_bit_cast(f16x2, u);
    return (v2f){(float)h.x, (float)h.y};
}

__global__ void prep_kernel(const float* __restrict__ drw1,
                            const float* __restrict__ drw2, const float* __restrict__ drb2,
                            const float* __restrict__ drw3, const float* __restrict__ drb3,
                            const float* __restrict__ dfw1,
                            const float* __restrict__ dfw2, const float* __restrict__ dfb2,
                            const float* __restrict__ dfw3, const float* __restrict__ dfb3,
                            const float* __restrict__ dtp, float* __restrict__ ws)
{
    int tid = threadIdx.x;
    for (int idx = tid; idx < 1024; idx += 256) {
        int k = idx >> 5, j = idx & 31;
        ws[W2P_F + 2 * idx]     = drw2[j * 32 + k];   // W2[j][k] pairs, k-major
        ws[W2P_F + 2 * idx + 1] = dfw2[j * 32 + k];
    }
    if (tid < 32) {
        ws[W1VP_F + 2 * tid]     = drw1[tid * 16 + 15];
        ws[W1VP_F + 2 * tid + 1] = dfw1[tid * 16 + 15];
        ws[W3P_F + 2 * tid]      = drw3[tid];
        ws[W3P_F + 2 * tid + 1]  = dfw3[tid];
        ws[B2P_F + 2 * tid]      = drb2[tid];
        ws[B2P_F + 2 * tid + 1]  = dfb2[tid];
    }
    if (tid == 0) {
        ws[CST_F]     = drb3[0];
        ws[CST_F + 1] = dfb3[0];
        ws[CST_F + 2] = dtp[0];
    }
}

// One block per path (192 lanes = 192 v-nodes). Weights via wave-uniform
// global reads -> pipelined s_loads. Output units in 2 passes of 16
// accumulators (h recomputed per pass) -> no spills (round-10 verified).
// Table values prescaled by INVD so the scan's state IS the table coord.
__global__ __attribute__((amdgpu_flat_work_group_size(NODES, NODES), amdgpu_waves_per_eu(4)))
void build_kernel(const float* __restrict__ sig,
                  const float* __restrict__ drw1, const float* __restrict__ drb1,
                  const float* __restrict__ dfw1, const float* __restrict__ dfb1,
                  const float* __restrict__ wconst, unsigned int* __restrict__ gtab)
{
    const int p = blockIdx.x;
    const int i = threadIdx.x;
    __shared__ v2f spv[32];            // pre pairs {dr, df} per hidden unit
    if (i < 64) {
        int j = i & 31, net = i >> 5;
        const float* w1 = net ? dfw1 : drw1;
        const float* b1 = net ? dfb1 : drb1;
        float acc = b1[j];
#pragma unroll
        for (int m = 0; m < 15; ++m) acc = fmaf(sig[p * 15 + m], w1[j * 16 + m], acc);
        ((float*)spv)[2 * j + net] = acc;
    }
    __syncthreads();

    const float v = VMIN + (WIDTHV / (float)(NODES - 1)) * (float)i;
    const v2f* __restrict__ w2p  = (const v2f*)(wconst + W2P_F);
    const v2f* __restrict__ w1vp = (const v2f*)(wconst + W1VP_F);
    const v2f* __restrict__ w3p  = (const v2f*)(wconst + W3P_F);
    const v2f* __restrict__ b2p  = (const v2f*)(wconst + B2P_F);

    v2f z3 = (v2f){wconst[CST_F], wconst[CST_F + 1]};

#pragma unroll
    for (int c = 0; c < 2; ++c) {          // two chunks of 16 output units
        v2f acc[16];
#pragma unroll
        for (int j = 0; j < 16; ++j) acc[j] = b2p[c * 16 + j];

#pragma unroll 8
        for (int k = 0; k < 32; ++k) {     // h recomputed per chunk (no big live array)
            v2f pre = spv[k];              // LDS broadcast (uniform addr)
            v2f z   = vfma(vsplat(v), w1vp[k], pre);
            v2f h   = tanh2(z);
            const v2f* col = w2p + k * 32 + c * 16;   // uniform -> s_load
#pragma unroll
            for (int j = 0; j < 16; ++j) acc[j] = vfma(col[j], h, acc[j]);
        }
#pragma unroll
        for (int j = 0; j < 16; ++j) {
            v2f a2 = tanh2(acc[j]);
            z3 = vfma(w3p[c * 16 + j], a2, z3);
        }
    }

    float dt = wconst[CST_F + 2];
    float fv = 3.0f * tanh1(z3.x) * dt * INVD;     // drift * dt * INVD (u-space)
    float gv = (sig1(z3.y) + 0.1f) * INVD;         // diffusion * INVD  (u-space)
    f16x2 o; o.x = (_Float16)fv; o.y = (_Float16)gv;
    gtab[(size_t)p * NODES + i] = __builtin_bit_cast(unsigned int, o);
}

// One lane per path, 64 paths per block. Table transposed in LDS:
// tab[node][lane] -> bank = lane%32 regardless of the data-dependent node
// index (2-way = free). State variable is u (table coordinate); per step:
// trunc -> addr -> 4 ds_reads -> CR poly -> u update. exp2 output off-chain.
__global__ __launch_bounds__(64) void scan_kernel(
    const float* __restrict__ init_var,
    const float* __restrict__ dW,
    const float* __restrict__ ws,
    float* __restrict__ out)
{
    __shared__ unsigned int tab[NODES][64];        // 48 KB, transposed
    const int lane  = threadIdx.x;
    const int pbase = blockIdx.x * 64;
    const unsigned int* __restrict__ gt = (const unsigned int*)((const char*)ws + GTAB_B);

    // coalesced global read; transposed LDS write (one-time)
    for (int p = 0; p < 64; ++p) {
        const unsigned int* row = gt + (size_t)(pbase + p) * NODES;
#pragma unroll
        for (int k = 0; k < NODES / 64; ++k)
            tab[k * 64 + lane][p] = row[k * 64 + lane];
    }
    __syncthreads();

    const int path = pbase + lane;
    float lv0 = logf(fminf(fmaxf(init_var[path], 0.005f), 0.2f));
    float u = fmaf(lv0, INVD, UOFFC);              // u in [1.73, 189.3]
    const float ULO = (-7.0f + 4.0f - VMIN) * INVD;
    const float UHI = (-0.5f + 4.0f - VMIN) * INVD;
    const float K1  = LFX / INVD;                  // ev = exp2(K1*u + K0)
    const float K0  = LFX * (VMIN - 4.0f);
    const float* __restrict__ dwrow = dW + (size_t)path * NT;
    float* __restrict__ outp = out + path;
    const unsigned int* __restrict__ tcol = &tab[0][lane];

    auto STEP = [&](float dw, int tt) {
        int   i  = (int)u;                          // trunc == floor (u > 0)
        float w  = u - (float)i;
        const unsigned int* n = tcol + (size_t)(i - 1) * 64;
        unsigned int qa = n[0], qb = n[64], qc = n[128], qd = n[192];
        v2f m1 = up16(qa), p0 = up16(qb), p1 = up16(qc), p2 = up16(qd);
        // Catmull-Rom: p0 + 0.5w*(d + w*(c2 + w*c3))
        v2f d  = p1 - m1;
        v2f c2 = (m1 + m1) - vsplat(5.0f) * p0 + vsplat(4.0f) * p1 - p2;
        v2f c3 = vsplat(3.0f) * (p0 - p1) + (p2 - m1);
        v2f val = vfma(vsplat(0.5f * w), vfma(vsplat(w), vfma(vsplat(w), c3, c2), d), p0);
        u = fmaf(val.y, dw, u + val.x);
        u = fminf(fmaxf(u, ULO), UHI);
        float ev = __builtin_amdgcn_exp2f(fmaf(u, K1, K0));   // off-chain
        __builtin_nontemporal_store(ev, outp + (size_t)tt * NPATH);
    };

    // 16-step-deep dW register pipeline (plain cached loads; lines reused 4x)
    v4f buf0 = *(const v4f*)(dwrow + 0);
    v4f buf1 = *(const v4f*)(dwrow + 4);
    v4f buf2 = *(const v4f*)(dwrow + 8);
    v4f buf3 = *(const v4f*)(dwrow + 12);
    for (int t = 0; t < NT; t += 4) {
        v4f cur = buf0;
        buf0 = buf1; buf1 = buf2; buf2 = buf3;
        if (t + 16 < NT) buf3 = *(const v4f*)(dwrow + t + 16);
        STEP(cur.x, t);
        STEP(cur.y, t + 1);
        STEP(cur.z, t + 2);
        STEP(cur.w, t + 3);
    }
}

extern "C" void kernel_launch(void* const* d_in, const int* in_sizes, int n_in,
                              void* d_out, int out_size, void* d_ws, size_t ws_size,
                              hipStream_t stream) {
    const float* init_var = (const float*)d_in[0];
    const float* sig      = (const float*)d_in[1];
    const float* dW       = (const float*)d_in[2];
    const float* dtp      = (const float*)d_in[3];
    const float* drw1     = (const float*)d_in[4];
    const float* drb1     = (const float*)d_in[5];
    const float* drw2     = (const float*)d_in[6];
    const float* drb2     = (const float*)d_in[7];
    const float* drw3     = (const float*)d_in[8];
    const float* drb3     = (const float*)d_in[9];
    const float* dfw1     = (const float*)d_in[10];
    const float* dfb1     = (const float*)d_in[11];
    const float* dfw2     = (const float*)d_in[12];
    const float* dfb2     = (const float*)d_in[13];
    const float* dfw3     = (const float*)d_in[14];
    const float* dfb3     = (const float*)d_in[15];
    float* out = (float*)d_out;
    float* ws  = (float*)d_ws;

    hipLaunchKernelGGL(prep_kernel, dim3(1), dim3(256), 0, stream,
                       drw1, drw2, drb2, drw3, drb3,
                       dfw1, dfw2, dfb2, dfw3, dfb3, dtp, ws);
    hipLaunchKernelGGL(build_kernel, dim3(NPATH), dim3(NODES), 0, stream,
                       sig, drw1, drb1, dfw1, dfb1,
                       ws, (unsigned int*)((char*)ws + GTAB_B));
    hipLaunchKernelGGL(scan_kernel, dim3(NPATH / 64), dim3(64), 0, stream,
                       init_var, dW, ws, out);
}

// Round 12
// 315.477 us; speedup vs baseline: 2.8340x; 1.1317x over previous
//
#include <hip/hip_runtime.h>
#include <math.h>

#define NPATH 8192
#define NT    2048
#define NODES 128
#define VMIN  (-3.06f)
#define WIDTHV 6.62f            // VMAX - VMIN = 3.56 - (-3.06)
#define SFX   2.8853900817779268f   // 2*log2(e)
#define LFX   1.4426950408889634f   // log2(e)
#define INVD  ((float)(NODES - 1) / WIDTHV)
#define UOFFC ((4.0f - VMIN) * INVD)

typedef float v2f __attribute__((ext_vector_type(2)));
typedef float v4f __attribute__((ext_vector_type(4)));

// ws float layout
#define W2P_F   0        // v2f w2pairs[k*32+j] = {W2dr[j][k], W2df[j][k]}  (2048 floats)
#define W1VP_F  2048     // v2f w1v pairs [32]
#define W3P_F   2112     // v2f w3 pairs  [32]
#define B2P_F   2176     // v2f b2 pairs  [32]
#define CST_F   2240     // b3dr, b3df, dt
#define GTAB_B  16384    // byte offset: v2f gtab[path][NODES] = {f*INVD, g*INVD} per node (8 MB)

__device__ __forceinline__ v2f vsplat(float x) { return (v2f){x, x}; }
__device__ __forceinline__ v2f vfma(v2f a, v2f b, v2f c) { return __builtin_elementwise_fma(a, b, c); }

__device__ __forceinline__ float tanh1(float z) {   // tanh(z) via exp2
    float e = __builtin_amdgcn_exp2f(SFX * z);
    return fmaf(__builtin_amdgcn_rcpf(1.0f + e), -2.0f, 1.0f);
}
__device__ __forceinline__ float sig1(float z) {    // sigmoid(z)
    float e = __builtin_amdgcn_exp2f(-LFX * z);
    return __builtin_amdgcn_rcpf(1.0f + e);
}
__device__ __forceinline__ v2f tanh2(v2f z) {
    v2f r; r.x = tanh1(z.x); r.y = tanh1(z.y); return r;
}

__global__ void prep_kernel(const float* __restrict__ drw1,
                            const float* __restrict__ drw2, const float* __restrict__ drb2,
                            const float* __restrict__ drw3, const float* __restrict__ drb3,
                            const float* __restrict__ dfw1,
                            const float* __restrict__ dfw2, const float* __restrict__ dfb2,
                            const float* __restrict__ dfw3, const float* __restrict__ dfb3,
                            const float* __restrict__ dtp, float* __restrict__ ws)
{
    int tid = threadIdx.x;
    for (int idx = tid; idx < 1024; idx += 256) {
        int k = idx >> 5, j = idx & 31;
        ws[W2P_F + 2 * idx]     = drw2[j * 32 + k];   // W2[j][k] pairs, k-major
        ws[W2P_F + 2 * idx + 1] = dfw2[j * 32 + k];
    }
    if (tid < 32) {
        ws[W1VP_F + 2 * tid]     = drw1[tid * 16 + 15];
        ws[W1VP_F + 2 * tid + 1] = dfw1[tid * 16 + 15];
        ws[W3P_F + 2 * tid]      = drw3[tid];
        ws[W3P_F + 2 * tid + 1]  = dfw3[tid];
        ws[B2P_F + 2 * tid]      = drb2[tid];
        ws[B2P_F + 2 * tid + 1]  = dfb2[tid];
    }
    if (tid == 0) {
        ws[CST_F]     = drb3[0];
        ws[CST_F + 1] = dfb3[0];
        ws[CST_F + 2] = dtp[0];
    }
}

// One block per path (128 lanes = 128 v-nodes). Weights via wave-uniform
// global reads -> pipelined s_loads. Output units in 2 passes of 16
// accumulators (h recomputed per pass) -> no spills (round-10/11 verified).
// Table values prescaled by INVD (u-space), written as fp32 pairs.
__global__ __attribute__((amdgpu_flat_work_group_size(NODES, NODES), amdgpu_waves_per_eu(4)))
void build_kernel(const float* __restrict__ sig,
                  const float* __restrict__ drw1, const float* __restrict__ drb1,
                  const float* __restrict__ dfw1, const float* __restrict__ dfb1,
                  const float* __restrict__ wconst, v2f* __restrict__ gtab)
{
    const int p = blockIdx.x;
    const int i = threadIdx.x;
    __shared__ v2f spv[32];            // pre pairs {dr, df} per hidden unit
    if (i < 64) {
        int j = i & 31, net = i >> 5;
        const float* w1 = net ? dfw1 : drw1;
        const float* b1 = net ? dfb1 : drb1;
        float acc = b1[j];
#pragma unroll
        for (int m = 0; m < 15; ++m) acc = fmaf(sig[p * 15 + m], w1[j * 16 + m], acc);
        ((float*)spv)[2 * j + net] = acc;
    }
    __syncthreads();

    const float v = VMIN + (WIDTHV / (float)(NODES - 1)) * (float)i;
    const v2f* __restrict__ w2p  = (const v2f*)(wconst + W2P_F);
    const v2f* __restrict__ w1vp = (const v2f*)(wconst + W1VP_F);
    const v2f* __restrict__ w3p  = (const v2f*)(wconst + W3P_F);
    const v2f* __restrict__ b2p  = (const v2f*)(wconst + B2P_F);

    v2f z3 = (v2f){wconst[CST_F], wconst[CST_F + 1]};

#pragma unroll
    for (int c = 0; c < 2; ++c) {          // two chunks of 16 output units
        v2f acc[16];
#pragma unroll
        for (int j = 0; j < 16; ++j) acc[j] = b2p[c * 16 + j];

#pragma unroll 8
        for (int k = 0; k < 32; ++k) {     // h recomputed per chunk (no big live array)
            v2f pre = spv[k];              // LDS broadcast (uniform addr)
            v2f z   = vfma(vsplat(v), w1vp[k], pre);
            v2f h   = tanh2(z);
            const v2f* col = w2p + k * 32 + c * 16;   // uniform -> s_load
#pragma unroll
            for (int j = 0; j < 16; ++j) acc[j] = vfma(col[j], h, acc[j]);
        }
#pragma unroll
        for (int j = 0; j < 16; ++j) {
            v2f a2 = tanh2(acc[j]);
            z3 = vfma(w3p[c * 16 + j], a2, z3);
        }
    }

    float dt = wconst[CST_F + 2];
    float fv = 3.0f * tanh1(z3.x) * dt * INVD;     // drift * dt * INVD (u-space)
    float gv = (sig1(z3.y) + 0.1f) * INVD;         // diffusion * INVD  (u-space)
    gtab[(size_t)p * NODES + i] = (v2f){fv, gv};
}

// One lane per path, 64 paths per block. fp32 table transposed in LDS:
// tab[node][lane] -> per-lane bank fixed regardless of node index. Node
// stride = 512 B so the 4 CR reads fuse to 2x ds_read2st64_b64. State is u
// (table coordinate); chain: cvt -> addr -> ds -> CR poly -> fma -> med3.
__global__ __launch_bounds__(64) void scan_kernel(
    const float* __restrict__ init_var,
    const float* __restrict__ dW,
    const float* __restrict__ ws,
    float* __restrict__ out)
{
    __shared__ v2f tab[NODES][64];                 // 64 KB, transposed
    const int lane  = threadIdx.x;
    const int pbase = blockIdx.x * 64;
    const v2f* __restrict__ gt = (const v2f*)((const char*)ws + GTAB_B);

    // coalesced global read; transposed LDS write (one-time)
    for (int p = 0; p < 64; ++p) {
        const v2f* row = gt + (size_t)(pbase + p) * NODES;
#pragma unroll
        for (int k = 0; k < NODES / 64; ++k)
            tab[k * 64 + lane][p] = row[k * 64 + lane];
    }
    __syncthreads();

    const int path = pbase + lane;
    float lv0 = logf(fminf(fmaxf(init_var[path], 0.005f), 0.2f));
    float u = fmaf(lv0, INVD, UOFFC);              // interior of [1.1, 125.9]
    const float ULO = (-7.0f + 4.0f - VMIN) * INVD;
    const float UHI = (-0.5f + 4.0f - VMIN) * INVD;
    const float K1  = LFX / INVD;                  // ev = exp2(K1*u + K0)
    const float K0  = LFX * (VMIN - 4.0f);
    const float* __restrict__ dwrow = dW + (size_t)path * NT;
    float* __restrict__ outp = out + path;
    const v2f* __restrict__ tbase = &tab[0][lane] - 64;   // -1 node folded in

    auto STEP = [&](float dw, int tt) {
        int   i  = (int)u;                          // trunc == floor (u > 0)
        float w  = __builtin_amdgcn_fractf(u);      // u - floor(u), 1 op
        const v2f* n = tbase + (size_t)i * 64;
        v2f m1 = n[0], p0 = n[64], p1 = n[128], p2 = n[192];
        // Catmull-Rom: p0 + 0.5w*(d + w*(c2 + w*c3))
        v2f d  = p1 - m1;
        v2f c2 = (m1 + m1) - vsplat(5.0f) * p0 + vsplat(4.0f) * p1 - p2;
        v2f c3 = vsplat(3.0f) * (p0 - p1) + (p2 - m1);
        v2f val = vfma(vsplat(0.5f * w), vfma(vsplat(w), vfma(vsplat(w), c3, c2), d), p0);
        u = fmaf(val.y, dw, u + val.x);
        u = __builtin_amdgcn_fmed3f(u, ULO, UHI);   // clamp, 1 op
        float ev = __builtin_amdgcn_exp2f(fmaf(u, K1, K0));   // off-chain
        __builtin_nontemporal_store(ev, outp + (size_t)tt * NPATH);
    };

    // 16-step-deep dW register pipeline (plain cached loads; lines reused 4x)
    v4f buf0 = *(const v4f*)(dwrow + 0);
    v4f buf1 = *(const v4f*)(dwrow + 4);
    v4f buf2 = *(const v4f*)(dwrow + 8);
    v4f buf3 = *(const v4f*)(dwrow + 12);
    for (int t = 0; t < NT; t += 4) {
        v4f cur = buf0;
        buf0 = buf1; buf1 = buf2; buf2 = buf3;
        if (t + 16 < NT) buf3 = *(const v4f*)(dwrow + t + 16);
        STEP(cur.x, t);
        STEP(cur.y, t + 1);
        STEP(cur.z, t + 2);
        STEP(cur.w, t + 3);
    }
}

extern "C" void kernel_launch(void* const* d_in, const int* in_sizes, int n_in,
                              void* d_out, int out_size, void* d_ws, size_t ws_size,
                              hipStream_t stream) {
    const float* init_var = (const float*)d_in[0];
    const float* sig      = (const float*)d_in[1];
    const float* dW       = (const float*)d_in[2];
    const float* dtp      = (const float*)d_in[3];
    const float* drw1     = (const float*)d_in[4];
    const float* drb1     = (const float*)d_in[5];
    const float* drw2     = (const float*)d_in[6];
    const float* drb2     = (const float*)d_in[7];
    const float* drw3     = (const float*)d_in[8];
    const float* drb3     = (const float*)d_in[9];
    const float* dfw1     = (const float*)d_in[10];
    const float* dfb1     = (const float*)d_in[11];
    const float* dfw2     = (const float*)d_in[12];
    const float* dfb2     = (const float*)d_in[13];
    const float* dfw3     = (const float*)d_in[14];
    const float* dfb3     = (const float*)d_in[15];
    float* out = (float*)d_out;
    float* ws  = (float*)d_ws;

    hipLaunchKernelGGL(prep_kernel, dim3(1), dim3(256), 0, stream,
                       drw1, drw2, drb2, drw3, drb3,
                       dfw1, dfw2, dfb2, dfw3, dfb3, dtp, ws);
    hipLaunchKernelGGL(build_kernel, dim3(NPATH), dim3(NODES), 0, stream,
                       sig, drw1, drb1, dfw1, dfb1,
                       ws, (v2f*)((char*)ws + GTAB_B));
    hipLaunchKernelGGL(scan_kernel, dim3(NPATH / 64), dim3(64), 0, stream,
                       init_var, dW, ws, out);
}